// Round 19
// baseline (97.828 us; speedup 1.0000x reference)
//
#include <hip/hip_runtime.h>

#define T_STEPS 65536
#define NZ 64
#define NH1 128
#define NH2 64
#define NEDGE 512
#define NCHUNK 8192
#define CL 8            // timesteps per chunk (T_STEPS / NCHUNK)
#define NSUPER 128
#define SUP_L 64        // chunks per super (NCHUNK / NSUPER)
#define STR 67          // h2t/lgT row stride in doubles (bank-conflict-tuned)
#define W2STR 68        // w2s row stride in floats (16B-aligned rows)

// ---- ws layout (bytes)
#define ADJ_OFF        0          // 64 * u64 (exported by block 0 for K4)
#define LG32_OFF       140288    // 64*T f32 (z-major: lg32[z*T + t]) = 16MB
#define FTAB_OFF       (LG32_OFF + (size_t)T_STEPS * NZ * 4)   // T*64 u8 = 4MB
#define CHUNKG_WS      (FTAB_OFF + (size_t)T_STEPS * NZ)       // 512KB
#define SUPERS_WS      (CHUNKG_WS + (size_t)NCHUNK * 64)       // 8KB

typedef unsigned long long ull;
typedef unsigned int u32;
typedef unsigned char u8;
typedef double f64x4 __attribute__((ext_vector_type(4)));
typedef float f32x4 __attribute__((ext_vector_type(4)));

// ---------------------------------------------------------------------------
// K2 (fused): prep + MFMA-f64 MLP + per-chunk transition tables.
// 512 threads = 8 waves; block owns 64 timesteps; 1024 blocks = 4/CU.
// Phase C is j-MAJOR: each wave makes ONE ascending pass over the 64 lgT
// rows (64 row reads vs ~208 in z-major), accumulating per-lane global
// max AND the neighbor-max of its 8 owned z's, gated by wave-uniform
// scalar adjacency bits (adj symmetric: adj[z]>>j == adj[j]>>z). The old
// C1a + cross-wave merge (pv/pi) phases and 2 barriers are deleted.
// region2 (5376B) overlaid, barrier-separated:
//   [always]  adj ull[64] at [0,512)
//   [layers]  base1s f64[128] at [512,1536) | w1ts f64[128] at [1536,2560)
//   [C2+]     F_lds u8[64][68] at [512,4864)
// ---------------------------------------------------------------------------
__global__ __launch_bounds__(512, 8) void mlp_tables_kernel(
    const float* __restrict__ times,
    const float* __restrict__ pa,
    const int* __restrict__ edges,
    const float* __restrict__ W1,
    const float* __restrict__ b1,
    const float* __restrict__ b2,
    const float* __restrict__ b3,
    const float* __restrict__ W2,
    const float* __restrict__ W3,
    unsigned char* __restrict__ ws_adj,
    float* __restrict__ lg32,
    unsigned char* __restrict__ chunkG,
    unsigned char* __restrict__ ftab) {
  __shared__ double region1[4352];      // 34816B: w2s f32[128][68] -> h2t/lgT f64[64][67]
  __shared__ double region2[672];       // 5376B: overlaid (see header)

  float* w2s = (float*)region1;             // [128][W2STR] f32
  double* h2t = region1;                    // [64 t][STR] f64
  double* lgT = region1;                    // [64 z][STR] f64
  ull* adj = (ull*)region2;                 // [64] at [0,512)
  double* base1s = region2 + 64;            // [128] f64 at [512,1536)
  double* w1ts = region2 + 192;             // [128] f64 at [1536,2560)
  u8* F_lds = (u8*)region2 + 512;           // [64][68] u8 at [512,4864)

  int tid = threadIdx.x, lane = tid & 63, wv = tid >> 6;
  int i15 = lane & 15, g = lane >> 4;
  int mt = wv & 3, nt0 = (wv >> 2) * 2;
  int t0 = blockIdx.x * 64;

  // ---- prep (per-block, deterministic): adjacency init
  if (tid < NZ) adj[tid] = 0ull;
  __syncthreads();  // barrier A: adj zeroed before atomicOr
  {
    int e0 = edges[tid];
    int e1 = edges[NEDGE + tid];
    atomicOr(&adj[e0], 1ull << e1);
    atomicOr(&adj[e1], 1ull << e0);
  }
  if (tid < NZ) atomicOr(&adj[tid], 1ull << tid);  // self loops
  // stage W2 via float4 (2048 vec4 / 512 threads = 4 iters)
  #pragma unroll
  for (int r = 0; r < 4; ++r) {
    int i = tid + r * 512;
    int row = i >> 4, c4 = (i & 15) << 2;
    *(f32x4*)&w2s[row * W2STR + c4] = *(const f32x4*)&W2[row * 64 + c4];
  }
  // base1/w1t f64 matvec (exact; identical in every block)
  if (tid < NH1) {
    double acc = (double)b1[tid];
    #pragma unroll 8
    for (int d = 0; d < 64; ++d)
      acc += (double)pa[d] * (double)W1[d * NH1 + tid];
    base1s[tid] = acc;
    w1ts[tid] = (double)W1[64 * NH1 + tid];
  }
  double tv = (double)times[t0 + mt * 16 + i15];
  // accumulator-init biases straight from global f32 (exact cvt)
  double bi20 = (double)b2[nt0 * 16 + i15], bi21 = (double)b2[nt0 * 16 + 16 + i15];
  double bi30 = (double)b3[nt0 * 16 + i15], bi31 = (double)b3[nt0 * 16 + 16 + i15];
  __syncthreads();  // barrier B: adj/w2s/base1s ready

  // block 0 exports adj for states_finalize (stream-ordered visibility)
  if (blockIdx.x == 0 && tid < NZ) ((ull*)ws_adj)[tid] = adj[tid];

  // ---- layer 2 (K=128, 32 MFMA k-steps x 2 N-tiles); W2 from LDS
  f64x4 c0, c1;
  c0[0] = bi20; c0[1] = bi20; c0[2] = bi20; c0[3] = bi20;
  c1[0] = bi21; c1[1] = bi21; c1[2] = bi21; c1[3] = bi21;
  #pragma unroll 8
  for (int ks = 0; ks < 32; ++ks) {
    int h = ks * 4 + g;
    double a = fma(tv, w1ts[h], base1s[h]);
    a = a > 0.0 ? a : 0.0;                      // h1 = relu(...), exact f64
    double b0 = (double)w2s[h * W2STR + nt0 * 16 + i15];
    double b1v = (double)w2s[h * W2STR + nt0 * 16 + 16 + i15];
    c0 = __builtin_amdgcn_mfma_f64_16x16x4f64(a, b0, c0, 0, 0, 0);
    c1 = __builtin_amdgcn_mfma_f64_16x16x4f64(a, b1v, c1, 0, 0, 0);
  }
  __syncthreads();  // barrier C: w2s + base1s/w1ts dead -> region1 = h2t
  #pragma unroll
  for (int r = 0; r < 4; ++r) {
    int t = mt * 16 + g * 4 + r;
    double v0 = c0[r] > 0.0 ? c0[r] : 0.0;      // relu(h2)
    double v1 = c1[r] > 0.0 ? c1[r] : 0.0;
    h2t[t * STR + nt0 * 16 + i15] = v0;
    h2t[t * STR + nt0 * 16 + 16 + i15] = v1;
  }
  __syncthreads();  // barrier D

  // ---- layer 3 (K=64, 16 MFMA k-steps x 2 N-tiles); W3 from global (L1)
  f64x4 d0, d1;
  d0[0] = bi30; d0[1] = bi30; d0[2] = bi30; d0[3] = bi30;
  d1[0] = bi31; d1[1] = bi31; d1[2] = bi31; d1[3] = bi31;
  #pragma unroll 8
  for (int ks = 0; ks < 16; ++ks) {
    int k = ks * 4 + g;
    double a3 = h2t[(mt * 16 + i15) * STR + k];
    double b0 = (double)W3[k * 64 + nt0 * 16 + i15];
    double b1v = (double)W3[k * 64 + nt0 * 16 + 16 + i15];
    d0 = __builtin_amdgcn_mfma_f64_16x16x4f64(a3, b0, d0, 0, 0, 0);
    d1 = __builtin_amdgcn_mfma_f64_16x16x4f64(a3, b1v, d1, 0, 0, 0);
  }
  __syncthreads();  // barrier E: h2 dead -> region1 becomes lgT
  #pragma unroll
  for (int r = 0; r < 4; ++r) {
    int t = mt * 16 + g * 4 + r;
    int z0 = nt0 * 16 + i15, z1 = z0 + 16;
    lgT[z0 * STR + t] = d0[r];
    lgT[z1 * STR + t] = d1[r];
  }
  __syncthreads();  // barrier F: lgT complete

  // ---- Phase C (j-major, lane = t): single ascending pass over 64 rows.
  // Accumulates per-lane global max (strict > = first-index ties) and the
  // 8 owned z's neighbor-maxes, gated by wave-uniform scalar adjacency
  // bits. Visit order ascending j + strict > == old semantics exactly.
  double vmax = -1.0e300;
  int jmax = 0;
  double vn[8];
  int jn[8];
  #pragma unroll
  for (int zz = 0; zz < 8; ++zz) { vn[zz] = -1.0e300; jn[zz] = 0; }
  int zbase = wv * 8;
  #pragma unroll 4
  for (int j = 0; j < 64; ++j) {
    double vj = lgT[j * STR + lane];
    // wave-uniform byte: which of my 8 z's neighbor j (adj symmetric)
    u32 bm = __builtin_amdgcn_readfirstlane((u32)(adj[j] >> zbase)) & 0xffu;
    if (vj > vmax) { vmax = vj; jmax = j; }
    #pragma unroll
    for (int zz = 0; zz < 8; ++zz) {
      if (bm & (1u << zz)) {
        if (vj > vn[zz]) { vn[zz] = vj; jn[zz] = j; }
      }
    }
  }
  double vgap = vmax - 1.0;
  #pragma unroll
  for (int zz = 0; zz < 8; ++zz) {
    int z = zbase + zz;
    ull az = adj[z];  // uniform-addr LDS broadcast
    int bit = (int)((az >> jmax) & 1ull);       // jmax per-lane
    int fnb = (vn[zz] > vgap) ? jn[zz]
            : ((vn[zz] < vgap) ? jmax : (jn[zz] < jmax ? jn[zz] : jmax));
    F_lds[lane * 68 + z] = (u8)(bit ? jmax : fnb);
  }
  __syncthreads();  // barrier G: F_lds complete

  // ---- Phase C3: coalesced ftab write
  u32* fo = (u32*)(ftab + (size_t)t0 * 64);
  #pragma unroll
  for (int r = 0; r < 2; ++r) {
    int i = tid + r * 512;            // 1024 words = 64t x 16 words
    int t = i >> 4, z4 = (i & 15) << 2;
    fo[i] = *(const u32*)&F_lds[t * 68 + z4];
  }

  // ---- Phase C4: compose this wave's chunk table (lane = z)
  int c = blockIdx.x * 8 + wv;
  int cur = lane;
  #pragma unroll
  for (int i = 0; i < CL; ++i) cur = F_lds[(wv * 8 + i) * 68 + cur];
  chunkG[(size_t)c * 64 + lane] = (u8)cur;

  // ---- Epilogue: coalesced lg32 stores (lgT in region1 still valid; no
  // barrier follows, so the store drain overlaps wave retirement).
  {
    int zb = wv * 8;
    #pragma unroll
    for (int zz = 0; zz < 8; ++zz) {
      double v = lgT[(zb + zz) * STR + lane];
      lg32[(size_t)(zb + zz) * T_STEPS + t0 + lane] = (float)v;
    }
  }
}

// ---------------------------------------------------------------------------
// K3: compose SUP_L chunk tables into each super table (LDS-staged).
// ---------------------------------------------------------------------------
__global__ __launch_bounds__(256) void super_compose_kernel(
    const unsigned char* __restrict__ chunkG,
    unsigned char* __restrict__ superS) {
  __shared__ u8 g[4][SUP_L * 64];  // 16KB
  int tid = threadIdx.x, lane = tid & 63, wv = tid >> 6;
  int k = blockIdx.x * 4 + wv;
  const u32* src = (const u32*)(chunkG + (size_t)k * SUP_L * 64);
  u32* dst = (u32*)g[wv];
  #pragma unroll 4
  for (int i = lane; i < SUP_L * 16; i += 64) dst[i] = src[i];
  // wave-private LDS region; compiler orders the dependent reads
  int cur = lane;
  #pragma unroll 8
  for (int c = 0; c < SUP_L; ++c) {
    int gg = g[wv][c * 64 + lane];
    cur = __shfl(gg, cur, 64);
  }
  superS[(size_t)k * 64 + lane] = (u8)cur;
}

// ---------------------------------------------------------------------------
// K4 (fused): per-chunk start states + finalize. 1024 blocks x 256 threads;
// block b owns 8 chunks [8b, 8b+8), all inside super k = b/8. lg32/ftab are
// prefetched into regs/LDS BEFORE the state walks so HBM/L2 latency hides.
// region is NSUPER*64 = 8KB: full ssup stage, then the 4KB chunkG tile
// overwrites its low half.
// ---------------------------------------------------------------------------
__global__ __launch_bounds__(256) void states_finalize_kernel(
    const float* __restrict__ lg32, const unsigned char* __restrict__ ws_ro,
    const unsigned char* __restrict__ chunkG,
    const unsigned char* __restrict__ superS,
    const unsigned char* __restrict__ ftab,
    float* __restrict__ out) {
  __shared__ u8 region[NSUPER * 64];    // 8KB: ssup, then chunkG tile (4KB)
  __shared__ ull adjs[64];
  __shared__ u8 fstage[4][2][CL * 64];  // 4KB
  int tid = threadIdx.x, lane = tid & 63, wv = tid >> 6;
  int b = blockIdx.x;
  int k = b >> 3;          // super index
  int myc = b * 8 + wv * 2;  // wave's first chunk

  if (tid < 64) adjs[tid] = ((const ull*)(ws_ro + ADJ_OFF))[tid];
  // stage ssup (8KB)
  for (int i = tid; i < NSUPER * 16; i += 256)
    ((u32*)region)[i] = ((const u32*)superS)[i];
  // prefetch logits (64B contiguous per lane across the wave's 2 chunks)
  float lgv[2][CL];
  #pragma unroll
  for (int cc = 0; cc < 2; ++cc)
    #pragma unroll
    for (int i = 0; i < CL; ++i)
      lgv[cc][i] = lg32[(size_t)lane * T_STEPS + (myc + cc) * CL + i];
  // prefetch F tables
  #pragma unroll
  for (int cc = 0; cc < 2; ++cc)
    for (int i = lane; i < CL * 16; i += 64)
      ((u32*)fstage[wv][cc])[i] =
          ((const u32*)(ftab + (size_t)(myc + cc) * CL * 64))[i];
  __syncthreads();

  // super prefix walk (uniform across all threads)
  int s = 0;
  for (int i = 0; i < k; ++i) s = region[i * 64 + s];
  __syncthreads();  // everyone done reading ssup
  // stage super k's chunkG tile (4KB, overwrites low half of region)
  {
    const u32* cg = (const u32*)(chunkG + (size_t)k * SUP_L * 64);
    for (int i = tid; i < SUP_L * 16; i += 256) ((u32*)region)[i] = cg[i];
  }
  __syncthreads();
  // walk to this block's chunk range, then through it capturing entries
  int lc0 = (b & 7) * 8;
  for (int c = 0; c < lc0; ++c) s = region[c * 64 + s];
  int e0 = 0, e1 = 0;
  #pragma unroll
  for (int j = 0; j < 8; ++j) {
    if (j == wv * 2) e0 = s;
    if (j == wv * 2 + 1) e1 = s;
    s = region[(lc0 + j) * 64 + s];
  }

  // finalize the wave's 2 chunks
  #pragma unroll
  for (int cc = 0; cc < 2; ++cc) {
    int st = cc ? e1 : e0;
    size_t tb = (size_t)(myc + cc) * CL * 64;
    #pragma unroll
    for (int i = 0; i < CL; ++i) {
      int bit = (int)((adjs[st] >> lane) & 1ull);
      float v = lgv[cc][i];
      out[tb + i * 64 + lane] = bit ? v : v - 1.0f;
      st = fstage[wv][cc][i * 64 + st];  // uniform broadcast read
    }
  }
}

// ---------------------------------------------------------------------------
extern "C" void kernel_launch(void* const* d_in, const int* in_sizes, int n_in,
                              void* d_out, int out_size, void* d_ws, size_t ws_size,
                              hipStream_t stream) {
  const float* pa    = (const float*)d_in[0];
  const float* times = (const float*)d_in[1];
  // d_in[2] zone_features: unused by the reference
  const int*   edges = (const int*)d_in[3];
  const float* W1    = (const float*)d_in[4];
  const float* b1    = (const float*)d_in[5];
  const float* W2    = (const float*)d_in[6];
  const float* b2    = (const float*)d_in[7];
  const float* W3    = (const float*)d_in[8];
  const float* b3    = (const float*)d_in[9];

  unsigned char* ws = (unsigned char*)d_ws;
  float* lg32 = (float*)(ws + LG32_OFF);
  unsigned char* ftab = ws + FTAB_OFF;
  unsigned char* chunkG = ws + CHUNKG_WS;
  unsigned char* superS = ws + SUPERS_WS;

  hipLaunchKernelGGL(mlp_tables_kernel, dim3(T_STEPS / 64), dim3(512), 0, stream,
                     times, pa, edges, W1, b1, b2, b3, W2, W3,
                     ws + ADJ_OFF, lg32, chunkG, ftab);
  hipLaunchKernelGGL(super_compose_kernel, dim3(NSUPER / 4), dim3(256), 0, stream,
                     chunkG, superS);
  hipLaunchKernelGGL(states_finalize_kernel, dim3(NCHUNK / 8), dim3(256), 0, stream,
                     lg32, ws, chunkG, superS, ftab, (float*)d_out);
}

// Round 20
// 75.128 us; speedup vs baseline: 1.3022x; 1.3022x over previous
//
#include <hip/hip_runtime.h>

#define T_STEPS 65536
#define NZ 64
#define NH1 128
#define NH2 64
#define NEDGE 512
#define NCHUNK 8192
#define CL 8            // timesteps per chunk (T_STEPS / NCHUNK)
#define NSUPER 128
#define SUP_L 64        // chunks per super (NCHUNK / NSUPER)
#define STR 67          // h2t/lgT row stride in doubles (bank-conflict-tuned)
#define W2STR 68        // w2s row stride in floats (16B-aligned rows)

// ---- ws layout (bytes)
#define ADJ_OFF        0          // 64 * u64 (exported by block 0 for K4)
#define LG32_OFF       140288    // 64*T f32 (z-major: lg32[z*T + t]) = 16MB
#define FTAB_OFF       (LG32_OFF + (size_t)T_STEPS * NZ * 4)   // T*64 u8 = 4MB
#define CHUNKG_WS      (FTAB_OFF + (size_t)T_STEPS * NZ)       // 512KB
#define SUPERS_WS      (CHUNKG_WS + (size_t)NCHUNK * 64)       // 8KB

typedef unsigned long long ull;
typedef unsigned int u32;
typedef unsigned char u8;
typedef double f64x4 __attribute__((ext_vector_type(4)));
typedef float f32x4 __attribute__((ext_vector_type(4)));

// ---------------------------------------------------------------------------
// K2 (fused): prep + MFMA-f64 MLP + per-chunk transition tables.
// 512 threads = 8 waves; block owns 64 timesteps; 1024 blocks = 4/CU.
// [REVERT to round-18 structure] C2 is z-MAJOR: per owned z, walk the
// adjacency bitmask 4 bits per iteration (scalar ctz extract, j0-padding,
// 4 LDS reads outstanding). Round-19's j-major variant traded LDS reads
// for 512 gated dual-cndmask updates -> VALUBusy 33->49%, +26us. z-major
// touches only true neighbors (~200 compares vs 512).
// region2 (5376B) overlaid, barrier-separated:
//   [always]  adj ull[64] at [0,512)
//   [layers]  base1s f64[128] at [512,1536) | w1ts f64[128] at [1536,2560)
//   [C1a/mrg] pv f64[8][64] at [512,4608) | pi u8[512] at [4608,5120)
//   [C2+]     F_lds u8[64][68] at [512,4864)
// ---------------------------------------------------------------------------
__global__ __launch_bounds__(512, 8) void mlp_tables_kernel(
    const float* __restrict__ times,
    const float* __restrict__ pa,
    const int* __restrict__ edges,
    const float* __restrict__ W1,
    const float* __restrict__ b1,
    const float* __restrict__ b2,
    const float* __restrict__ b3,
    const float* __restrict__ W2,
    const float* __restrict__ W3,
    unsigned char* __restrict__ ws_adj,
    float* __restrict__ lg32,
    unsigned char* __restrict__ chunkG,
    unsigned char* __restrict__ ftab) {
  __shared__ double region1[4352];      // 34816B: w2s f32[128][68] -> h2t/lgT f64[64][67]
  __shared__ double region2[672];       // 5376B: overlaid (see header)

  float* w2s = (float*)region1;             // [128][W2STR] f32
  double* h2t = region1;                    // [64 t][STR] f64
  double* lgT = region1;                    // [64 z][STR] f64
  ull* adj = (ull*)region2;                 // [64] at [0,512)
  double* base1s = region2 + 64;            // [128] f64 at [512,1536)
  double* w1ts = region2 + 192;             // [128] f64 at [1536,2560)
  double* pv = region2 + 64;                // [8][64] f64 at [512,4608)
  u8* pi = (u8*)region2 + 4608;             // [8][64] u8 at [4608,5120)
  u8* F_lds = (u8*)region2 + 512;           // [64][68] u8 at [512,4864)

  int tid = threadIdx.x, lane = tid & 63, wv = tid >> 6;
  int i15 = lane & 15, g = lane >> 4;
  int mt = wv & 3, nt0 = (wv >> 2) * 2;
  int t0 = blockIdx.x * 64;

  // ---- prep (per-block, deterministic): adjacency init
  if (tid < NZ) adj[tid] = 0ull;
  __syncthreads();  // barrier A: adj zeroed before atomicOr
  {
    int e0 = edges[tid];
    int e1 = edges[NEDGE + tid];
    atomicOr(&adj[e0], 1ull << e1);
    atomicOr(&adj[e1], 1ull << e0);
  }
  if (tid < NZ) atomicOr(&adj[tid], 1ull << tid);  // self loops
  // stage W2 via float4 (2048 vec4 / 512 threads = 4 iters)
  #pragma unroll
  for (int r = 0; r < 4; ++r) {
    int i = tid + r * 512;
    int row = i >> 4, c4 = (i & 15) << 2;
    *(f32x4*)&w2s[row * W2STR + c4] = *(const f32x4*)&W2[row * 64 + c4];
  }
  // base1/w1t f64 matvec (exact; identical in every block)
  if (tid < NH1) {
    double acc = (double)b1[tid];
    #pragma unroll 8
    for (int d = 0; d < 64; ++d)
      acc += (double)pa[d] * (double)W1[d * NH1 + tid];
    base1s[tid] = acc;
    w1ts[tid] = (double)W1[64 * NH1 + tid];
  }
  double tv = (double)times[t0 + mt * 16 + i15];
  // accumulator-init biases straight from global f32 (exact cvt)
  double bi20 = (double)b2[nt0 * 16 + i15], bi21 = (double)b2[nt0 * 16 + 16 + i15];
  double bi30 = (double)b3[nt0 * 16 + i15], bi31 = (double)b3[nt0 * 16 + 16 + i15];
  __syncthreads();  // barrier B: adj/w2s/base1s ready

  // block 0 exports adj for states_finalize (stream-ordered visibility)
  if (blockIdx.x == 0 && tid < NZ) ((ull*)ws_adj)[tid] = adj[tid];

  // ---- layer 2 (K=128, 32 MFMA k-steps x 2 N-tiles); W2 from LDS
  f64x4 c0, c1;
  c0[0] = bi20; c0[1] = bi20; c0[2] = bi20; c0[3] = bi20;
  c1[0] = bi21; c1[1] = bi21; c1[2] = bi21; c1[3] = bi21;
  #pragma unroll 8
  for (int ks = 0; ks < 32; ++ks) {
    int h = ks * 4 + g;
    double a = fma(tv, w1ts[h], base1s[h]);
    a = a > 0.0 ? a : 0.0;                      // h1 = relu(...), exact f64
    double b0 = (double)w2s[h * W2STR + nt0 * 16 + i15];
    double b1v = (double)w2s[h * W2STR + nt0 * 16 + 16 + i15];
    c0 = __builtin_amdgcn_mfma_f64_16x16x4f64(a, b0, c0, 0, 0, 0);
    c1 = __builtin_amdgcn_mfma_f64_16x16x4f64(a, b1v, c1, 0, 0, 0);
  }
  __syncthreads();  // w2s + base1s/w1ts dead -> region1 becomes h2t
  #pragma unroll
  for (int r = 0; r < 4; ++r) {
    int t = mt * 16 + g * 4 + r;
    double v0 = c0[r] > 0.0 ? c0[r] : 0.0;      // relu(h2)
    double v1 = c1[r] > 0.0 ? c1[r] : 0.0;
    h2t[t * STR + nt0 * 16 + i15] = v0;
    h2t[t * STR + nt0 * 16 + 16 + i15] = v1;
  }
  __syncthreads();

  // ---- layer 3 (K=64, 16 MFMA k-steps x 2 N-tiles); W3 from global (L1)
  f64x4 d0, d1;
  d0[0] = bi30; d0[1] = bi30; d0[2] = bi30; d0[3] = bi30;
  d1[0] = bi31; d1[1] = bi31; d1[2] = bi31; d1[3] = bi31;
  #pragma unroll 8
  for (int ks = 0; ks < 16; ++ks) {
    int k = ks * 4 + g;
    double a3 = h2t[(mt * 16 + i15) * STR + k];
    double b0 = (double)W3[k * 64 + nt0 * 16 + i15];
    double b1v = (double)W3[k * 64 + nt0 * 16 + 16 + i15];
    d0 = __builtin_amdgcn_mfma_f64_16x16x4f64(a3, b0, d0, 0, 0, 0);
    d1 = __builtin_amdgcn_mfma_f64_16x16x4f64(a3, b1v, d1, 0, 0, 0);
  }
  __syncthreads();  // h2 dead -> region1 becomes lgT
  #pragma unroll
  for (int r = 0; r < 4; ++r) {
    int t = mt * 16 + g * 4 + r;
    int z0 = nt0 * 16 + i15, z1 = z0 + 16;
    lgT[z0 * STR + t] = d0[r];
    lgT[z1 * STR + t] = d1[r];
  }
  __syncthreads();

  // ---- Phase C1a (LDS-only): wave wv scans z rows [8wv,8wv+8) (lane = t).
  // Ascending z, strict > keeps first index.
  {
    int zb = wv * 8;
    double vm = lgT[zb * STR + lane];
    int jm = zb;
    #pragma unroll
    for (int zz = 1; zz < 8; ++zz) {
      double v = lgT[(zb + zz) * STR + lane];
      if (v > vm) { vm = v; jm = zb + zz; }
    }
    pv[wv * 64 + lane] = vm;
    pi[wv * 64 + lane] = (u8)jm;
  }
  __syncthreads();
  double vmax = pv[lane];
  int jmax = pi[lane];
  #pragma unroll
  for (int w = 1; w < 8; ++w) {
    double v = pv[w * 64 + lane];
    int j = pi[w * 64 + lane];
    if (v > vmax) { vmax = v; jmax = j; }  // ascending w keeps smallest z on ties
  }
  double vgap = vmax - 1.0;
  __syncthreads();  // pv/pi dead before F_lds overlay-writes

  // ---- Phase C2: F[t][z] via 4-wide adjacency-bitmask walk. Scalar ctz
  // extracts up to 4 ascending j's per iteration (padded with j0 — padding
  // repeats an already-compared index, so strict > keeps semantics exact);
  // the 4 lgT row reads issue back-to-back (4 outstanding lgkm ops).
  #pragma unroll
  for (int zz = 0; zz < 8; ++zz) {
    int z = __builtin_amdgcn_readfirstlane(wv * 8 + zz);
    ull az = adj[z];  // uniform-addr LDS broadcast
    // scalarize the mask so the walk bookkeeping runs on the scalar pipe
    u32 mlo = __builtin_amdgcn_readfirstlane((u32)az);
    u32 mhi = __builtin_amdgcn_readfirstlane((u32)(az >> 32));
    ull m = ((ull)mhi << 32) | mlo;
    double vn = -1.0e300;
    int jn = 0;
    while (m) {
      int j0 = __builtin_ctzll(m); m &= m - 1;
      int j1 = j0, j2 = j0, j3 = j0;
      if (m) { j1 = __builtin_ctzll(m); m &= m - 1; }
      if (m) { j2 = __builtin_ctzll(m); m &= m - 1; }
      if (m) { j3 = __builtin_ctzll(m); m &= m - 1; }
      double v0 = lgT[j0 * STR + lane];
      double v1 = lgT[j1 * STR + lane];
      double v2 = lgT[j2 * STR + lane];
      double v3 = lgT[j3 * STR + lane];
      if (v0 > vn) { vn = v0; jn = j0; }   // ascending, strict >
      if (v1 > vn) { vn = v1; jn = j1; }
      if (v2 > vn) { vn = v2; jn = j2; }
      if (v3 > vn) { vn = v3; jn = j3; }
    }
    int bit = (int)((az >> jmax) & 1ull);
    int fnb = (vn > vgap) ? jn : ((vn < vgap) ? jmax : (jn < jmax ? jn : jmax));
    F_lds[lane * 68 + z] = (u8)(bit ? jmax : fnb);
  }
  __syncthreads();

  // ---- Phase C3: coalesced ftab write
  u32* fo = (u32*)(ftab + (size_t)t0 * 64);
  #pragma unroll
  for (int r = 0; r < 2; ++r) {
    int i = tid + r * 512;            // 1024 words = 64t x 16 words
    int t = i >> 4, z4 = (i & 15) << 2;
    fo[i] = *(const u32*)&F_lds[t * 68 + z4];
  }

  // ---- Phase C4: compose this wave's chunk table (lane = z)
  int c = blockIdx.x * 8 + wv;
  int cur = lane;
  #pragma unroll
  for (int i = 0; i < CL; ++i) cur = F_lds[(wv * 8 + i) * 68 + cur];
  chunkG[(size_t)c * 64 + lane] = (u8)cur;

  // ---- Epilogue: coalesced lg32 stores (lgT in region1 still valid; no
  // barrier follows, so the store drain overlaps wave retirement).
  {
    int zb = wv * 8;
    #pragma unroll
    for (int zz = 0; zz < 8; ++zz) {
      double v = lgT[(zb + zz) * STR + lane];
      lg32[(size_t)(zb + zz) * T_STEPS + t0 + lane] = (float)v;
    }
  }
}

// ---------------------------------------------------------------------------
// K3: compose SUP_L chunk tables into each super table (LDS-staged).
// ---------------------------------------------------------------------------
__global__ __launch_bounds__(256) void super_compose_kernel(
    const unsigned char* __restrict__ chunkG,
    unsigned char* __restrict__ superS) {
  __shared__ u8 g[4][SUP_L * 64];  // 16KB
  int tid = threadIdx.x, lane = tid & 63, wv = tid >> 6;
  int k = blockIdx.x * 4 + wv;
  const u32* src = (const u32*)(chunkG + (size_t)k * SUP_L * 64);
  u32* dst = (u32*)g[wv];
  #pragma unroll 4
  for (int i = lane; i < SUP_L * 16; i += 64) dst[i] = src[i];
  // wave-private LDS region; compiler orders the dependent reads
  int cur = lane;
  #pragma unroll 8
  for (int c = 0; c < SUP_L; ++c) {
    int gg = g[wv][c * 64 + lane];
    cur = __shfl(gg, cur, 64);
  }
  superS[(size_t)k * 64 + lane] = (u8)cur;
}

// ---------------------------------------------------------------------------
// K4 (fused): per-chunk start states + finalize. 1024 blocks x 256 threads;
// block b owns 8 chunks [8b, 8b+8), all inside super k = b/8. lg32/ftab are
// prefetched into regs/LDS BEFORE the state walks so HBM/L2 latency hides.
// region is NSUPER*64 = 8KB: full ssup stage, then the 4KB chunkG tile
// overwrites its low half.
// ---------------------------------------------------------------------------
__global__ __launch_bounds__(256) void states_finalize_kernel(
    const float* __restrict__ lg32, const unsigned char* __restrict__ ws_ro,
    const unsigned char* __restrict__ chunkG,
    const unsigned char* __restrict__ superS,
    const unsigned char* __restrict__ ftab,
    float* __restrict__ out) {
  __shared__ u8 region[NSUPER * 64];    // 8KB: ssup, then chunkG tile (4KB)
  __shared__ ull adjs[64];
  __shared__ u8 fstage[4][2][CL * 64];  // 4KB
  int tid = threadIdx.x, lane = tid & 63, wv = tid >> 6;
  int b = blockIdx.x;
  int k = b >> 3;          // super index
  int myc = b * 8 + wv * 2;  // wave's first chunk

  if (tid < 64) adjs[tid] = ((const ull*)(ws_ro + ADJ_OFF))[tid];
  // stage ssup (8KB)
  for (int i = tid; i < NSUPER * 16; i += 256)
    ((u32*)region)[i] = ((const u32*)superS)[i];
  // prefetch logits (64B contiguous per lane across the wave's 2 chunks)
  float lgv[2][CL];
  #pragma unroll
  for (int cc = 0; cc < 2; ++cc)
    #pragma unroll
    for (int i = 0; i < CL; ++i)
      lgv[cc][i] = lg32[(size_t)lane * T_STEPS + (myc + cc) * CL + i];
  // prefetch F tables
  #pragma unroll
  for (int cc = 0; cc < 2; ++cc)
    for (int i = lane; i < CL * 16; i += 64)
      ((u32*)fstage[wv][cc])[i] =
          ((const u32*)(ftab + (size_t)(myc + cc) * CL * 64))[i];
  __syncthreads();

  // super prefix walk (uniform across all threads)
  int s = 0;
  for (int i = 0; i < k; ++i) s = region[i * 64 + s];
  __syncthreads();  // everyone done reading ssup
  // stage super k's chunkG tile (4KB, overwrites low half of region)
  {
    const u32* cg = (const u32*)(chunkG + (size_t)k * SUP_L * 64);
    for (int i = tid; i < SUP_L * 16; i += 256) ((u32*)region)[i] = cg[i];
  }
  __syncthreads();
  // walk to this block's chunk range, then through it capturing entries
  int lc0 = (b & 7) * 8;
  for (int c = 0; c < lc0; ++c) s = region[c * 64 + s];
  int e0 = 0, e1 = 0;
  #pragma unroll
  for (int j = 0; j < 8; ++j) {
    if (j == wv * 2) e0 = s;
    if (j == wv * 2 + 1) e1 = s;
    s = region[(lc0 + j) * 64 + s];
  }

  // finalize the wave's 2 chunks
  #pragma unroll
  for (int cc = 0; cc < 2; ++cc) {
    int st = cc ? e1 : e0;
    size_t tb = (size_t)(myc + cc) * CL * 64;
    #pragma unroll
    for (int i = 0; i < CL; ++i) {
      int bit = (int)((adjs[st] >> lane) & 1ull);
      float v = lgv[cc][i];
      out[tb + i * 64 + lane] = bit ? v : v - 1.0f;
      st = fstage[wv][cc][i * 64 + st];  // uniform broadcast read
    }
  }
}

// ---------------------------------------------------------------------------
extern "C" void kernel_launch(void* const* d_in, const int* in_sizes, int n_in,
                              void* d_out, int out_size, void* d_ws, size_t ws_size,
                              hipStream_t stream) {
  const float* pa    = (const float*)d_in[0];
  const float* times = (const float*)d_in[1];
  // d_in[2] zone_features: unused by the reference
  const int*   edges = (const int*)d_in[3];
  const float* W1    = (const float*)d_in[4];
  const float* b1    = (const float*)d_in[5];
  const float* W2    = (const float*)d_in[6];
  const float* b2    = (const float*)d_in[7];
  const float* W3    = (const float*)d_in[8];
  const float* b3    = (const float*)d_in[9];

  unsigned char* ws = (unsigned char*)d_ws;
  float* lg32 = (float*)(ws + LG32_OFF);
  unsigned char* ftab = ws + FTAB_OFF;
  unsigned char* chunkG = ws + CHUNKG_WS;
  unsigned char* superS = ws + SUPERS_WS;

  hipLaunchKernelGGL(mlp_tables_kernel, dim3(T_STEPS / 64), dim3(512), 0, stream,
                     times, pa, edges, W1, b1, b2, b3, W2, W3,
                     ws + ADJ_OFF, lg32, chunkG, ftab);
  hipLaunchKernelGGL(super_compose_kernel, dim3(NSUPER / 4), dim3(256), 0, stream,
                     chunkG, superS);
  hipLaunchKernelGGL(states_finalize_kernel, dim3(NCHUNK / 8), dim3(256), 0, stream,
                     lg32, ws, chunkG, superS, ftab, (float*)d_out);
}